// Round 1
// baseline (698.267 us; speedup 1.0000x reference)
//
#include <hip/hip_runtime.h>
#include <math.h>

#define B_ 4
#define T_ 4096
#define E_ 512
#define H_ 8
#define D_ 64
#define TOPK 24
#define NROW (B_*T_)
#define FH 2049
#define FHP 2064
#define PI_F 3.14159265358979323846f

// ---------------- GEMM: C[n,m] = sum_k A[n,k]*W[m,k] + bias[m] ----------------
// A: [N,K] row-major. W: [M,K] row-major. Tiles 128x128, BK=8, 256 thr, 8x8/thread.
__global__ __launch_bounds__(256) void gemm_nt(const float* __restrict__ A,
                                               const float* __restrict__ W,
                                               const float* __restrict__ bias,
                                               float* __restrict__ C,
                                               int K, int M)
{
    __shared__ float As[8][128];
    __shared__ float Ws[8][128];
    const int tid = threadIdx.x;
    const int m0 = blockIdx.x * 128;
    const int n0 = blockIdx.y * 128;
    const int tm = tid & 15;        // column group (fast within wave -> coalesced C writes)
    const int tn = tid >> 4;        // row group
    const int lrow = tid >> 1;      // 0..127 for staging loads
    const int lk4  = (tid & 1) * 4; // 0 or 4

    float acc[8][8];
#pragma unroll
    for (int i = 0; i < 8; i++)
#pragma unroll
        for (int j = 0; j < 8; j++) acc[i][j] = 0.f;

    for (int k0 = 0; k0 < K; k0 += 8) {
        float4 av = *(const float4*)&A[(size_t)(n0 + lrow) * K + k0 + lk4];
        float4 wv = *(const float4*)&W[(size_t)(m0 + lrow) * K + k0 + lk4];
        __syncthreads();
        As[lk4 + 0][lrow] = av.x; As[lk4 + 1][lrow] = av.y;
        As[lk4 + 2][lrow] = av.z; As[lk4 + 3][lrow] = av.w;
        Ws[lk4 + 0][lrow] = wv.x; Ws[lk4 + 1][lrow] = wv.y;
        Ws[lk4 + 2][lrow] = wv.z; Ws[lk4 + 3][lrow] = wv.w;
        __syncthreads();
#pragma unroll
        for (int kk = 0; kk < 8; kk++) {
            float a[8], b[8];
            *(float4*)&a[0] = *(float4*)&As[kk][4 * tn];
            *(float4*)&a[4] = *(float4*)&As[kk][64 + 4 * tn];
            *(float4*)&b[0] = *(float4*)&Ws[kk][4 * tm];
            *(float4*)&b[4] = *(float4*)&Ws[kk][64 + 4 * tm];
#pragma unroll
            for (int i = 0; i < 8; i++)
#pragma unroll
                for (int j = 0; j < 8; j++)
                    acc[i][j] += a[i] * b[j];
        }
    }

    float4 b0 = *(const float4*)&bias[m0 + 4 * tm];
    float4 b1 = *(const float4*)&bias[m0 + 64 + 4 * tm];
#pragma unroll
    for (int i = 0; i < 8; i++) {
        int n = n0 + ((i < 4) ? (4 * tn + i) : (64 + 4 * tn + (i - 4)));
        float4 o0, o1;
        o0.x = acc[i][0] + b0.x; o0.y = acc[i][1] + b0.y;
        o0.z = acc[i][2] + b0.z; o0.w = acc[i][3] + b0.w;
        o1.x = acc[i][4] + b1.x; o1.y = acc[i][5] + b1.y;
        o1.z = acc[i][6] + b1.z; o1.w = acc[i][7] + b1.w;
        *(float4*)&C[(size_t)n * M + m0 + 4 * tm] = o0;
        *(float4*)&C[(size_t)n * M + m0 + 64 + 4 * tm] = o1;
    }
}

// ---------------- transpose [B,T,E] -> [B,E,T] ----------------
__global__ __launch_bounds__(256) void transpose_kernel(const float* __restrict__ in,
                                                        float* __restrict__ out)
{
    __shared__ float tile[32][33];
    const int b = blockIdx.z;
    const int t0 = blockIdx.x * 32, e0 = blockIdx.y * 32;
    const int tx = threadIdx.x & 31, ty = threadIdx.x >> 5; // ty 0..7
#pragma unroll
    for (int i = 0; i < 4; i++) {
        int t = t0 + ty + i * 8;
        tile[ty + i * 8][tx] = in[((size_t)b * T_ + t) * E_ + e0 + tx];
    }
    __syncthreads();
#pragma unroll
    for (int i = 0; i < 4; i++) {
        int e = e0 + ty + i * 8;
        out[((size_t)b * E_ + e) * T_ + t0 + tx] = tile[tx][ty + i * 8];
    }
}

__device__ __forceinline__ int rev12(int x) { return (int)(__brev((unsigned)x) >> 20); }

// ---------------- forward FFT per (b,e): z = Q + iK, product spectrum ----------------
__global__ __launch_bounds__(512) void fft_fwd_kernel(const float* __restrict__ Qt,
                                                      const float* __restrict__ Kt,
                                                      float2* __restrict__ prod)
{
    __shared__ float re[4096];
    __shared__ float im[4096];
    const int be = blockIdx.x;  // b*E + e
    const int tid = threadIdx.x;
    const float* qrow = Qt + (size_t)be * T_;
    const float* krow = Kt + (size_t)be * T_;
#pragma unroll
    for (int s = 0; s < 8; s++) {
        int t = tid + 512 * s;
        re[t] = qrow[t];
        im[t] = krow[t];
    }
    __syncthreads();
    // radix-2 DIF, natural in -> bit-reversed out
    for (int st = 11; st >= 0; st--) {
        const int m = 1 << st;
        const float angf = -PI_F / (float)m;
#pragma unroll
        for (int s = 0; s < 4; s++) {
            int j = tid + 512 * s;           // 0..2047
            int k = j & (m - 1);
            int i0 = ((j >> st) << (st + 1)) | k;
            int i1 = i0 + m;
            float ux = re[i0], uy = im[i0];
            float vx = re[i1], vy = im[i1];
            re[i0] = ux + vx; im[i0] = uy + vy;
            float dx = ux - vx, dy = uy - vy;
            float sn, cs;
            __sincosf(angf * (float)k, &sn, &cs);
            re[i1] = dx * cs - dy * sn;
            im[i1] = dx * sn + dy * cs;
        }
        __syncthreads();
    }
    // unpack packed real FFTs and write Qf * conj(Kf) for f = 0..2048
    float2* out = prod + (size_t)be * FHP;
#pragma unroll
    for (int s = 0; s < 5; s++) {
        int f = tid + 512 * s;
        if (f > 2048) break;
        if (s == 4 && tid != 0) break;     // only f = 2048 extra
        int pf = rev12(f);
        int pn = rev12((T_ - f) & (T_ - 1));
        float Ax = re[pf], Ay = im[pf];
        float Bx = re[pn], By = im[pn];
        float qx = 0.5f * (Ax + Bx), qy = 0.5f * (Ay - By);
        float kx = 0.5f * (Ay + By), ky = -0.5f * (Ax - Bx);
        float2 p;
        p.x = qx * kx + qy * ky;           // Re(Qf * conj(Kf))
        p.y = qy * kx - qx * ky;           // Im(Qf * conj(Kf))
        out[f] = p;
    }
}

// ---------------- reduce product spectra over channels ----------------
__global__ __launch_bounds__(256) void reduce_s(const float2* __restrict__ prod,
                                                float2* __restrict__ S)
{
    const int f = blockIdx.x * 256 + threadIdx.x;
    const int b = blockIdx.y;
    if (f >= FH) return;
    float sx = 0.f, sy = 0.f;
    const float2* p = prod + (size_t)b * E_ * FHP + f;
#pragma unroll 8
    for (int e = 0; e < E_; e++) {
        float2 v = p[(size_t)e * FHP];
        sx += v.x; sy += v.y;
    }
    S[b * FHP + f] = make_float2(sx, sy);
}

// ---------------- inverse FFT -> ac_mean ----------------
__global__ __launch_bounds__(512) void ifft_kernel(const float2* __restrict__ S,
                                                   float* __restrict__ acm)
{
    __shared__ float re[4096];
    __shared__ float im[4096];
    const int b = blockIdx.x, tid = threadIdx.x;
#pragma unroll
    for (int s = 0; s < 4; s++) {
        int f = tid + 512 * s;              // 0..2047
        float2 v = S[b * FHP + f];
        re[f] = v.x; im[f] = v.y;
        if (f >= 1) { re[T_ - f] = v.x; im[T_ - f] = -v.y; }
    }
    if (tid == 0) {
        float2 v = S[b * FHP + 2048];
        re[2048] = v.x; im[2048] = v.y;
    }
    __syncthreads();
    for (int st = 11; st >= 0; st--) {
        const int m = 1 << st;
        const float angf = PI_F / (float)m;   // + sign: inverse
#pragma unroll
        for (int s = 0; s < 4; s++) {
            int j = tid + 512 * s;
            int k = j & (m - 1);
            int i0 = ((j >> st) << (st + 1)) | k;
            int i1 = i0 + m;
            float ux = re[i0], uy = im[i0];
            float vx = re[i1], vy = im[i1];
            re[i0] = ux + vx; im[i0] = uy + vy;
            float dx = ux - vx, dy = uy - vy;
            float sn, cs;
            __sincosf(angf * (float)k, &sn, &cs);
            re[i1] = dx * cs - dy * sn;
            im[i1] = dx * sn + dy * cs;
        }
        __syncthreads();
    }
    const float scale = 1.0f / ((float)T_ * (float)E_);
#pragma unroll
    for (int s = 0; s < 8; s++) {
        int p = tid + 512 * s;
        acm[b * T_ + rev12(p)] = re[p] * scale;
    }
}

// ---------------- top-k (24) + softmax, per batch ----------------
__global__ __launch_bounds__(256) void topk_kernel(const float* __restrict__ acm,
                                                   int* __restrict__ delays,
                                                   float* __restrict__ weights)
{
    __shared__ float vals[4096];
    __shared__ float bv[256];
    __shared__ int   bi[256];
    __shared__ float topv[TOPK];
    const int b = blockIdx.x, tid = threadIdx.x;
#pragma unroll
    for (int s = 0; s < 16; s++) vals[tid + 256 * s] = acm[b * T_ + tid + 256 * s];
    __syncthreads();
    for (int it = 0; it < TOPK; it++) {
        float best = -INFINITY; int bidx = 0;
#pragma unroll
        for (int s = 0; s < 16; s++) {
            int idx = tid * 16 + s;          // ascending scan -> lowest-index tie-break
            float v = vals[idx];
            if (v > best) { best = v; bidx = idx; }
        }
        bv[tid] = best; bi[tid] = bidx;
        __syncthreads();
        for (int off = 128; off > 0; off >>= 1) {
            if (tid < off) {
                if (bv[tid + off] > bv[tid] ||
                    (bv[tid + off] == bv[tid] && bi[tid + off] < bi[tid])) {
                    bv[tid] = bv[tid + off]; bi[tid] = bi[tid + off];
                }
            }
            __syncthreads();
        }
        if (tid == 0) {
            delays[b * TOPK + it] = bi[0];
            topv[it] = bv[0];
            vals[bi[0]] = -INFINITY;
        }
        __syncthreads();
    }
    if (tid == 0) {
        float mx = topv[0];
        float w[TOPK], sum = 0.f;
        for (int i = 0; i < TOPK; i++) { w[i] = expf(topv[i] - mx); sum += w[i]; }
        for (int i = 0; i < TOPK; i++) weights[b * TOPK + i] = w[i] / sum;
    }
}

// ---------------- agg: weighted circular gather of V ----------------
__global__ __launch_bounds__(256) void agg_kernel(const float* __restrict__ V,
                                                  const int* __restrict__ delays,
                                                  const float* __restrict__ weights,
                                                  float* __restrict__ agg)
{
    __shared__ int   dly[B_][TOPK];
    __shared__ float wt[B_][TOPK];
    const int b = blockIdx.y;
    const int tid = threadIdx.x;
    if (tid < B_ * TOPK) {
        dly[tid / TOPK][tid % TOPK] = delays[tid];
        wt[tid / TOPK][tid % TOPK]  = weights[tid];
    }
    __syncthreads();
    const int e4 = tid & 127;           // float4 index over E
    const int r  = tid >> 7;            // 0..1
    const int t  = blockIdx.x * 2 + r;
    const int h  = e4 >> 4;
    const int c  = (b * H_ + h) % B_;   // reference's tile() quirk: row j uses batch j % B
    float4 acc = make_float4(0.f, 0.f, 0.f, 0.f);
    const float4* Vb = (const float4*)V + (size_t)b * T_ * 128;
#pragma unroll
    for (int i = 0; i < TOPK; i++) {
        int tt = (t + dly[c][i]) & (T_ - 1);
        float4 v = Vb[(size_t)tt * 128 + e4];
        float w = wt[c][i];
        acc.x += w * v.x; acc.y += w * v.y; acc.z += w * v.z; acc.w += w * v.w;
    }
    ((float4*)agg)[((size_t)b * T_ + t) * 128 + e4] = acc;
}

// ---------------- launch ----------------
extern "C" void kernel_launch(void* const* d_in, const int* in_sizes, int n_in,
                              void* d_out, int out_size, void* d_ws, size_t ws_size,
                              hipStream_t stream)
{
    const float* hidden = (const float*)d_in[0];
    const float* Wq = (const float*)d_in[1]; const float* bq = (const float*)d_in[2];
    const float* Wk = (const float*)d_in[3]; const float* bk = (const float*)d_in[4];
    const float* Wv = (const float*)d_in[5]; const float* bv = (const float*)d_in[6];
    const float* Wo = (const float*)d_in[7]; const float* bo = (const float*)d_in[8];

    char* ws = (char*)d_ws;
    const size_t QT_OFF  = 0;                       // 32 MB
    const size_t KT_OFF  = 33554432;                // 32 MB
    const size_t V_OFF   = 67108864;                // 32 MB
    const size_t BIG_OFF = 100663296;               // 34 MB: stage(Qn/Kn) -> prod -> agg
    const size_t S_OFF   = BIG_OFF + 33816576;      // 66 KB
    const size_t ACM_OFF = S_OFF + 66048;           // 64 KB
    const size_t DEL_OFF = ACM_OFF + 65536;         // 384 B
    const size_t WTS_OFF = DEL_OFF + 384;           // 384 B
    if (ws_size < WTS_OFF + 384) return;            // workspace too small -> fail visibly

    float*  Qt     = (float*)(ws + QT_OFF);
    float*  Kt     = (float*)(ws + KT_OFF);
    float*  V      = (float*)(ws + V_OFF);
    float*  stage  = (float*)(ws + BIG_OFF);
    float2* prod   = (float2*)(ws + BIG_OFF);
    float*  aggb   = (float*)(ws + BIG_OFF);
    float2* S      = (float2*)(ws + S_OFF);
    float*  acm    = (float*)(ws + ACM_OFF);
    int*    delays = (int*)(ws + DEL_OFF);
    float*  wts    = (float*)(ws + WTS_OFF);

    dim3 gg(E_ / 128, NROW / 128);   // (4, 128)
    dim3 tg(T_ / 32, E_ / 32, B_);   // (128, 16, 4)

    // Q -> stage -> Qt(transposed)
    gemm_nt<<<gg, 256, 0, stream>>>(hidden, Wq, bq, stage, E_, E_);
    transpose_kernel<<<tg, 256, 0, stream>>>(stage, Qt);
    // K -> stage -> Kt(transposed)
    gemm_nt<<<gg, 256, 0, stream>>>(hidden, Wk, bk, stage, E_, E_);
    transpose_kernel<<<tg, 256, 0, stream>>>(stage, Kt);
    // V (natural layout)
    gemm_nt<<<gg, 256, 0, stream>>>(hidden, Wv, bv, V, E_, E_);

    // autocorrelation spectrum
    fft_fwd_kernel<<<B_ * E_, 512, 0, stream>>>(Qt, Kt, prod);
    dim3 rg((FH + 255) / 256, B_);   // (9, 4)
    reduce_s<<<rg, 256, 0, stream>>>(prod, S);
    ifft_kernel<<<B_, 512, 0, stream>>>(S, acm);
    topk_kernel<<<B_, 256, 0, stream>>>(acm, delays, wts);

    // weighted circular gather + output projection
    dim3 ag(T_ / 2, B_);
    agg_kernel<<<ag, 256, 0, stream>>>(V, delays, wts, aggb);
    gemm_nt<<<gg, 256, 0, stream>>>(aggb, Wo, bo, (float*)d_out, E_, E_);
}

// Round 2
// 300.959 us; speedup vs baseline: 2.3201x; 2.3201x over previous
//
#include <hip/hip_runtime.h>
#include <math.h>

#define B_ 4
#define T_ 4096
#define E_ 512
#define H_ 8
#define TOPK 24
#define FH 2049
#define FHP 2064
#define PI_F 3.14159265358979323846f

typedef __attribute__((ext_vector_type(8))) short bf16x8;
typedef __attribute__((ext_vector_type(4))) float f32x4;

__device__ __forceinline__ unsigned short f2bf(float f) {
    unsigned u = __float_as_uint(f);
    u = (u + 0x7FFFu + ((u >> 16) & 1u)) >> 16;
    return (unsigned short)u;
}
__device__ __forceinline__ float bf2f(unsigned short h) {
    return __uint_as_float(((unsigned)h) << 16);
}

// ---------------- fp32 -> bf16 hi/lo split ----------------
__global__ __launch_bounds__(256) void split_hidden(const float* __restrict__ x,
                                                    unsigned short* __restrict__ hi,
                                                    unsigned short* __restrict__ lo)
{
    int i = (blockIdx.x * 256 + threadIdx.x) * 4;
    float4 v = *(const float4*)&x[i];
    float f[4] = {v.x, v.y, v.z, v.w};
    unsigned short hh[4], ll[4];
#pragma unroll
    for (int j = 0; j < 4; j++) {
        hh[j] = f2bf(f[j]);
        ll[j] = f2bf(f[j] - bf2f(hh[j]));
    }
    *(ushort4*)&hi[i] = make_ushort4(hh[0], hh[1], hh[2], hh[3]);
    *(ushort4*)&lo[i] = make_ushort4(ll[0], ll[1], ll[2], ll[3]);
}

__global__ __launch_bounds__(256) void split_w4(const float* __restrict__ w0,
                                                const float* __restrict__ w1,
                                                const float* __restrict__ w2,
                                                const float* __restrict__ w3,
                                                unsigned short* __restrict__ hi,
                                                unsigned short* __restrict__ lo)
{
    const float* src = (blockIdx.y == 0) ? w0 : (blockIdx.y == 1) ? w1
                     : (blockIdx.y == 2) ? w2 : w3;
    size_t off = (size_t)blockIdx.y * (E_ * E_);
    int i = (blockIdx.x * 256 + threadIdx.x) * 4;
    float4 v = *(const float4*)&src[i];
    float f[4] = {v.x, v.y, v.z, v.w};
    unsigned short hh[4], ll[4];
#pragma unroll
    for (int j = 0; j < 4; j++) {
        hh[j] = f2bf(f[j]);
        ll[j] = f2bf(f[j] - bf2f(hh[j]));
    }
    *(ushort4*)&hi[off + i] = make_ushort4(hh[0], hh[1], hh[2], hh[3]);
    *(ushort4*)&lo[off + i] = make_ushort4(ll[0], ll[1], ll[2], ll[3]);
}

// ---------------- MFMA GEMM: C[n,m] = sum_k A[n,k]*W[m,k] + bias[m] ----------------
// PASSES: 1 = single bf16, 3 = split (AhWh + AhWl + AlWh).
// OMODE: 0 = natural fp32 [N,512], 1 = transposed fp32 [B,E,T], 2 = natural bf16.
template<int PASSES, int OMODE>
__global__ __launch_bounds__(256) void mfma_gemm(const unsigned short* __restrict__ Ah,
                                                 const unsigned short* __restrict__ Al,
                                                 const unsigned short* __restrict__ Bh,
                                                 const unsigned short* __restrict__ Bl,
                                                 const float* __restrict__ bias,
                                                 void* __restrict__ Cp)
{
    constexpr int NT = (PASSES == 3) ? 4 : 2;
    constexpr int TSZ = 128 * 40;            // padded tile: 128 rows x 40 shorts (80B stride)
    __shared__ short smem[NT * TSZ];
    const int tid = threadIdx.x;
    const int m0 = blockIdx.x * 128;
    const int n0 = blockIdx.y * 128;
    const int wid = tid >> 6, lane = tid & 63;
    const int wn = wid >> 1, wm = wid & 1;
    const int lr = lane & 15, lg = lane >> 4;
    const int kb = lg * 8;

    short* At  = smem;
    short* Alt = smem + ((PASSES == 3) ? TSZ : 0);
    short* Bt  = smem + ((PASSES == 3) ? 2 : 1) * TSZ;
    short* Blt = smem + ((PASSES == 3) ? 3 : 1) * TSZ;

    f32x4 acc[4][4];
#pragma unroll
    for (int i = 0; i < 4; i++)
#pragma unroll
        for (int j = 0; j < 4; j++) acc[i][j] = (f32x4)0.f;

    const int c0 = tid, c1 = tid + 256;
    const int r0 = c0 >> 2, kp0 = (c0 & 3) << 3;
    const int r1 = c1 >> 2, kp1 = (c1 & 3) << 3;

    for (int k0 = 0; k0 < 512; k0 += 32) {
        __syncthreads();
        *(bf16x8*)&At[r0 * 40 + kp0] = *(const bf16x8*)&Ah[(size_t)(n0 + r0) * 512 + k0 + kp0];
        *(bf16x8*)&At[r1 * 40 + kp1] = *(const bf16x8*)&Ah[(size_t)(n0 + r1) * 512 + k0 + kp1];
        *(bf16x8*)&Bt[r0 * 40 + kp0] = *(const bf16x8*)&Bh[(size_t)(m0 + r0) * 512 + k0 + kp0];
        *(bf16x8*)&Bt[r1 * 40 + kp1] = *(const bf16x8*)&Bh[(size_t)(m0 + r1) * 512 + k0 + kp1];
        if (PASSES == 3) {
            *(bf16x8*)&Alt[r0 * 40 + kp0] = *(const bf16x8*)&Al[(size_t)(n0 + r0) * 512 + k0 + kp0];
            *(bf16x8*)&Alt[r1 * 40 + kp1] = *(const bf16x8*)&Al[(size_t)(n0 + r1) * 512 + k0 + kp1];
            *(bf16x8*)&Blt[r0 * 40 + kp0] = *(const bf16x8*)&Bl[(size_t)(m0 + r0) * 512 + k0 + kp0];
            *(bf16x8*)&Blt[r1 * 40 + kp1] = *(const bf16x8*)&Bl[(size_t)(m0 + r1) * 512 + k0 + kp1];
        }
        __syncthreads();
        bf16x8 a[4], b[4];
#pragma unroll
        for (int f = 0; f < 4; f++) {
            a[f] = *(bf16x8*)&At[(wn * 64 + f * 16 + lr) * 40 + kb];
            b[f] = *(bf16x8*)&Bt[(wm * 64 + f * 16 + lr) * 40 + kb];
        }
        if (PASSES == 3) {
            bf16x8 a2[4], b2[4];
#pragma unroll
            for (int f = 0; f < 4; f++) {
                a2[f] = *(bf16x8*)&Alt[(wn * 64 + f * 16 + lr) * 40 + kb];
                b2[f] = *(bf16x8*)&Blt[(wm * 64 + f * 16 + lr) * 40 + kb];
            }
#pragma unroll
            for (int i = 0; i < 4; i++)
#pragma unroll
                for (int j = 0; j < 4; j++) {
                    acc[i][j] = __builtin_amdgcn_mfma_f32_16x16x32_bf16(a[i], b[j], acc[i][j], 0, 0, 0);
                    acc[i][j] = __builtin_amdgcn_mfma_f32_16x16x32_bf16(a[i], b2[j], acc[i][j], 0, 0, 0);
                    acc[i][j] = __builtin_amdgcn_mfma_f32_16x16x32_bf16(a2[i], b[j], acc[i][j], 0, 0, 0);
                }
        } else {
#pragma unroll
            for (int i = 0; i < 4; i++)
#pragma unroll
                for (int j = 0; j < 4; j++)
                    acc[i][j] = __builtin_amdgcn_mfma_f32_16x16x32_bf16(a[i], b[j], acc[i][j], 0, 0, 0);
        }
    }

    float bs[4];
#pragma unroll
    for (int j = 0; j < 4; j++) bs[j] = bias[m0 + wm * 64 + j * 16 + lr];

    if (OMODE == 1) {
        // transposed write to [B, E, T]: per-fragment t is contiguous -> float4
        float* C = (float*)Cp;
        const int bidx = n0 >> 12;
        const int t0 = (n0 & 4095) + wn * 64;
#pragma unroll
        for (int i = 0; i < 4; i++)
#pragma unroll
            for (int j = 0; j < 4; j++) {
                int t = t0 + i * 16 + lg * 4;
                int e = m0 + wm * 64 + j * 16 + lr;
                float4 o = make_float4(acc[i][j][0] + bs[j], acc[i][j][1] + bs[j],
                                       acc[i][j][2] + bs[j], acc[i][j][3] + bs[j]);
                *(float4*)&C[((size_t)(bidx * 512 + e)) * 4096 + t] = o;
            }
    } else if (OMODE == 0) {
        float* C = (float*)Cp;
#pragma unroll
        for (int i = 0; i < 4; i++)
#pragma unroll
            for (int j = 0; j < 4; j++) {
                int m = m0 + wm * 64 + j * 16 + lr;
#pragma unroll
                for (int r = 0; r < 4; r++) {
                    int n = n0 + wn * 64 + i * 16 + lg * 4 + r;
                    C[(size_t)n * 512 + m] = acc[i][j][r] + bs[j];
                }
            }
    } else {
        unsigned short* C = (unsigned short*)Cp;
#pragma unroll
        for (int i = 0; i < 4; i++)
#pragma unroll
            for (int j = 0; j < 4; j++) {
                int m = m0 + wm * 64 + j * 16 + lr;
#pragma unroll
                for (int r = 0; r < 4; r++) {
                    int n = n0 + wn * 64 + i * 16 + lg * 4 + r;
                    C[(size_t)n * 512 + m] = f2bf(acc[i][j][r] + bs[j]);
                }
            }
    }
}

__device__ __forceinline__ int rev12(int x) { return (int)(__brev((unsigned)x) >> 20); }

// ---------------- forward FFT per (b,e): z = Q + iK, product spectrum ----------------
__global__ __launch_bounds__(512) void fft_fwd_kernel(const float* __restrict__ Qt,
                                                      const float* __restrict__ Kt,
                                                      float2* __restrict__ prod)
{
    __shared__ float re[4096];
    __shared__ float im[4096];
    const int be = blockIdx.x;
    const int tid = threadIdx.x;
    const float* qrow = Qt + (size_t)be * T_;
    const float* krow = Kt + (size_t)be * T_;
#pragma unroll
    for (int s = 0; s < 8; s++) {
        int t = tid + 512 * s;
        re[t] = qrow[t];
        im[t] = krow[t];
    }
    __syncthreads();
    for (int st = 11; st >= 0; st--) {
        const int m = 1 << st;
        const float angf = -PI_F / (float)m;
#pragma unroll
        for (int s = 0; s < 4; s++) {
            int j = tid + 512 * s;
            int k = j & (m - 1);
            int i0 = ((j >> st) << (st + 1)) | k;
            int i1 = i0 + m;
            float ux = re[i0], uy = im[i0];
            float vx = re[i1], vy = im[i1];
            re[i0] = ux + vx; im[i0] = uy + vy;
            float dx = ux - vx, dy = uy - vy;
            float sn, cs;
            __sincosf(angf * (float)k, &sn, &cs);
            re[i1] = dx * cs - dy * sn;
            im[i1] = dx * sn + dy * cs;
        }
        __syncthreads();
    }
    float2* out = prod + (size_t)be * FHP;
#pragma unroll
    for (int s = 0; s < 5; s++) {
        int f = tid + 512 * s;
        if (f > 2048) break;
        if (s == 4 && tid != 0) break;
        int pf = rev12(f);
        int pn = rev12((T_ - f) & (T_ - 1));
        float Ax = re[pf], Ay = im[pf];
        float Bx = re[pn], By = im[pn];
        float qx = 0.5f * (Ax + Bx), qy = 0.5f * (Ay - By);
        float kx = 0.5f * (Ay + By), ky = -0.5f * (Ax - Bx);
        float2 p;
        p.x = qx * kx + qy * ky;
        p.y = qy * kx - qx * ky;
        out[f] = p;
    }
}

// ---------------- reduce product spectra over channels ----------------
__global__ __launch_bounds__(256) void reduce_s(const float2* __restrict__ prod,
                                                float2* __restrict__ S)
{
    const int f = blockIdx.x * 256 + threadIdx.x;
    const int b = blockIdx.y;
    if (f >= FH) return;
    float sx = 0.f, sy = 0.f;
    const float2* p = prod + (size_t)b * E_ * FHP + f;
#pragma unroll 8
    for (int e = 0; e < E_; e++) {
        float2 v = p[(size_t)e * FHP];
        sx += v.x; sy += v.y;
    }
    S[b * FHP + f] = make_float2(sx, sy);
}

// ---------------- inverse FFT -> ac_mean ----------------
__global__ __launch_bounds__(512) void ifft_kernel(const float2* __restrict__ S,
                                                   float* __restrict__ acm)
{
    __shared__ float re[4096];
    __shared__ float im[4096];
    const int b = blockIdx.x, tid = threadIdx.x;
#pragma unroll
    for (int s = 0; s < 4; s++) {
        int f = tid + 512 * s;
        float2 v = S[b * FHP + f];
        re[f] = v.x; im[f] = v.y;
        if (f >= 1) { re[T_ - f] = v.x; im[T_ - f] = -v.y; }
    }
    if (tid == 0) {
        float2 v = S[b * FHP + 2048];
        re[2048] = v.x; im[2048] = v.y;
    }
    __syncthreads();
    for (int st = 11; st >= 0; st--) {
        const int m = 1 << st;
        const float angf = PI_F / (float)m;
#pragma unroll
        for (int s = 0; s < 4; s++) {
            int j = tid + 512 * s;
            int k = j & (m - 1);
            int i0 = ((j >> st) << (st + 1)) | k;
            int i1 = i0 + m;
            float ux = re[i0], uy = im[i0];
            float vx = re[i1], vy = im[i1];
            re[i0] = ux + vx; im[i0] = uy + vy;
            float dx = ux - vx, dy = uy - vy;
            float sn, cs;
            __sincosf(angf * (float)k, &sn, &cs);
            re[i1] = dx * cs - dy * sn;
            im[i1] = dx * sn + dy * cs;
        }
        __syncthreads();
    }
    const float scale = 1.0f / ((float)T_ * (float)E_);
#pragma unroll
    for (int s = 0; s < 8; s++) {
        int p = tid + 512 * s;
        acm[b * T_ + rev12(p)] = re[p] * scale;
    }
}

// ---------------- top-k (24) + softmax, per batch ----------------
__global__ __launch_bounds__(256) void topk_kernel(const float* __restrict__ acm,
                                                   int* __restrict__ delays,
                                                   float* __restrict__ weights)
{
    __shared__ float vals[4096];
    __shared__ float bv[256];
    __shared__ int   bi[256];
    __shared__ float topv[TOPK];
    const int b = blockIdx.x, tid = threadIdx.x;
#pragma unroll
    for (int s = 0; s < 16; s++) vals[tid + 256 * s] = acm[b * T_ + tid + 256 * s];
    __syncthreads();
    for (int it = 0; it < TOPK; it++) {
        float best = -INFINITY; int bidx = 0;
#pragma unroll
        for (int s = 0; s < 16; s++) {
            int idx = tid * 16 + s;
            float v = vals[idx];
            if (v > best) { best = v; bidx = idx; }
        }
        bv[tid] = best; bi[tid] = bidx;
        __syncthreads();
        for (int off = 128; off > 0; off >>= 1) {
            if (tid < off) {
                if (bv[tid + off] > bv[tid] ||
                    (bv[tid + off] == bv[tid] && bi[tid + off] < bi[tid])) {
                    bv[tid] = bv[tid + off]; bi[tid] = bi[tid + off];
                }
            }
            __syncthreads();
        }
        if (tid == 0) {
            delays[b * TOPK + it] = bi[0];
            topv[it] = bv[0];
            vals[bi[0]] = -INFINITY;
        }
        __syncthreads();
    }
    if (tid == 0) {
        float mx = topv[0];
        float w[TOPK], sum = 0.f;
        for (int i = 0; i < TOPK; i++) { w[i] = expf(topv[i] - mx); sum += w[i]; }
        for (int i = 0; i < TOPK; i++) weights[b * TOPK + i] = w[i] / sum;
    }
}

// ---------------- agg: weighted circular gather of bf16 V ----------------
__global__ __launch_bounds__(256) void agg_kernel(const unsigned short* __restrict__ V,
                                                  const int* __restrict__ delays,
                                                  const float* __restrict__ wts,
                                                  unsigned short* __restrict__ agg)
{
    __shared__ int   dly[B_][TOPK];
    __shared__ float wt[B_][TOPK];
    const int tid = threadIdx.x, b = blockIdx.y;
    if (tid < B_ * TOPK) {
        dly[tid / TOPK][tid % TOPK] = delays[tid];
        wt[tid / TOPK][tid % TOPK]  = wts[tid];
    }
    __syncthreads();
    const int lane = tid & 63, w = tid >> 6;
    const int t = blockIdx.x * 4 + w;
    const int e8 = lane * 8;
    const int h = e8 >> 6;
    const int c = (b * H_ + h) % B_;
    const unsigned short* Vb = V + (size_t)b * T_ * E_;
    float acc[8];
#pragma unroll
    for (int j = 0; j < 8; j++) acc[j] = 0.f;
#pragma unroll
    for (int i = 0; i < TOPK; i++) {
        int tt = (t + dly[c][i]) & (T_ - 1);
        bf16x8 v = *(const bf16x8*)&Vb[(size_t)tt * E_ + e8];
        float wg = wt[c][i];
#pragma unroll
        for (int j = 0; j < 8; j++)
            acc[j] += wg * bf2f((unsigned short)v[j]);
    }
    bf16x8 o;
#pragma unroll
    for (int j = 0; j < 8; j++) o[j] = (short)f2bf(acc[j]);
    *(bf16x8*)&agg[((size_t)b * T_ + t) * E_ + e8] = o;
}

// ---------------- launch ----------------
extern "C" void kernel_launch(void* const* d_in, const int* in_sizes, int n_in,
                              void* d_out, int out_size, void* d_ws, size_t ws_size,
                              hipStream_t stream)
{
    const float* hidden = (const float*)d_in[0];
    const float* Wq = (const float*)d_in[1]; const float* bq = (const float*)d_in[2];
    const float* Wk = (const float*)d_in[3]; const float* bk = (const float*)d_in[4];
    const float* Wv = (const float*)d_in[5]; const float* bv = (const float*)d_in[6];
    const float* Wo = (const float*)d_in[7]; const float* bo = (const float*)d_in[8];

    char* ws = (char*)d_ws;
    const size_t QT_OFF  = 0;                  // 33.5 MB fp32 [B,E,T]
    const size_t KT_OFF  = 33554432;           // 33.5 MB
    const size_t VB_OFF  = 67108864;           // 16.8 MB bf16 [B,T,E]
    const size_t BIG_OFF = 83886080;           // 33.8 MB: Ah+Al -> prod -> agg_bf16
    const size_t WHI_OFF = 117702656;          // 2 MB  (4x 512x512 bf16)
    const size_t WLO_OFF = 119799808;          // 2 MB
    const size_t S_OFF   = 121896960;          // 66 KB
    const size_t ACM_OFF = 121963008;          // 64 KB
    const size_t DEL_OFF = 122028544;          // 384 B
    const size_t WTS_OFF = 122028928;          // 384 B
    if (ws_size < 122029312) return;

    float*  Qt   = (float*)(ws + QT_OFF);
    float*  Kt   = (float*)(ws + KT_OFF);
    unsigned short* Vb  = (unsigned short*)(ws + VB_OFF);
    unsigned short* Ah  = (unsigned short*)(ws + BIG_OFF);
    unsigned short* Al  = (unsigned short*)(ws + BIG_OFF + 16777216);
    float2* prod = (float2*)(ws + BIG_OFF);
    unsigned short* Ag  = (unsigned short*)(ws + BIG_OFF);
    unsigned short* Whi = (unsigned short*)(ws + WHI_OFF);
    unsigned short* Wlo = (unsigned short*)(ws + WLO_OFF);
    float2* S    = (float2*)(ws + S_OFF);
    float*  acm  = (float*)(ws + ACM_OFF);
    int*    delays = (int*)(ws + DEL_OFF);
    float*  wts    = (float*)(ws + WTS_OFF);

    unsigned short* Wqh = Whi + 0 * 262144; unsigned short* Wql = Wlo + 0 * 262144;
    unsigned short* Wkh = Whi + 1 * 262144; unsigned short* Wkl = Wlo + 1 * 262144;
    unsigned short* Wvh = Whi + 2 * 262144;
    unsigned short* Woh = Whi + 3 * 262144;

    // splits
    split_hidden<<<8192, 256, 0, stream>>>(hidden, Ah, Al);
    dim3 wg(256, 4);
    split_w4<<<wg, 256, 0, stream>>>(Wq, Wk, Wv, Wo, Whi, Wlo);

    // GEMMs
    dim3 gg(4, 128);
    mfma_gemm<3, 1><<<gg, 256, 0, stream>>>(Ah, Al, Wqh, Wql, bq, Qt);
    mfma_gemm<3, 1><<<gg, 256, 0, stream>>>(Ah, Al, Wkh, Wkl, bk, Kt);
    mfma_gemm<1, 2><<<gg, 256, 0, stream>>>(Ah, Ah, Wvh, Wvh, bv, Vb);

    // autocorrelation spectrum
    fft_fwd_kernel<<<B_ * E_, 512, 0, stream>>>(Qt, Kt, prod);
    dim3 rg((FH + 255) / 256, B_);
    reduce_s<<<rg, 256, 0, stream>>>(prod, S);
    ifft_kernel<<<B_, 512, 0, stream>>>(S, acm);
    topk_kernel<<<B_, 256, 0, stream>>>(acm, delays, wts);

    // weighted circular gather (bf16 in/out) + output projection
    dim3 ag(T_ / 4, B_);
    agg_kernel<<<ag, 256, 0, stream>>>(Vb, delays, wts, Ag);
    mfma_gemm<1, 0><<<gg, 256, 0, stream>>>(Ag, Ag, Woh, Woh, bo, (float*)d_out);
}

// Round 3
// 231.342 us; speedup vs baseline: 3.0183x; 1.3009x over previous
//
#include <hip/hip_runtime.h>
#include <math.h>

#define B_ 4
#define T_ 4096
#define E_ 512
#define H_ 8
#define TOPK 24
#define FH 2049
#define FHP 2064

typedef __attribute__((ext_vector_type(8))) short bf16x8;
typedef __attribute__((ext_vector_type(4))) float f32x4;

__device__ __forceinline__ unsigned short f2bf(float f) {
    unsigned u = __float_as_uint(f);
    u = (u + 0x7FFFu + ((u >> 16) & 1u)) >> 16;
    return (unsigned short)u;
}
__device__ __forceinline__ float bf2f(unsigned short h) {
    return __uint_as_float(((unsigned)h) << 16);
}

// ---------------- fp32 -> bf16 hi/lo split ----------------
__global__ __launch_bounds__(256) void split_hidden(const float* __restrict__ x,
                                                    unsigned short* __restrict__ hi,
                                                    unsigned short* __restrict__ lo)
{
    int i = (blockIdx.x * 256 + threadIdx.x) * 4;
    float4 v = *(const float4*)&x[i];
    float f[4] = {v.x, v.y, v.z, v.w};
    unsigned short hh[4], ll[4];
#pragma unroll
    for (int j = 0; j < 4; j++) {
        hh[j] = f2bf(f[j]);
        ll[j] = f2bf(f[j] - bf2f(hh[j]));
    }
    *(ushort4*)&hi[i] = make_ushort4(hh[0], hh[1], hh[2], hh[3]);
    *(ushort4*)&lo[i] = make_ushort4(ll[0], ll[1], ll[2], ll[3]);
}

__global__ __launch_bounds__(256) void split_w4(const float* __restrict__ w0,
                                                const float* __restrict__ w1,
                                                const float* __restrict__ w2,
                                                const float* __restrict__ w3,
                                                unsigned short* __restrict__ hi,
                                                unsigned short* __restrict__ lo)
{
    const float* src = (blockIdx.y == 0) ? w0 : (blockIdx.y == 1) ? w1
                     : (blockIdx.y == 2) ? w2 : w3;
    size_t off = (size_t)blockIdx.y * (E_ * E_);
    int i = (blockIdx.x * 256 + threadIdx.x) * 4;
    float4 v = *(const float4*)&src[i];
    float f[4] = {v.x, v.y, v.z, v.w};
    unsigned short hh[4], ll[4];
#pragma unroll
    for (int j = 0; j < 4; j++) {
        hh[j] = f2bf(f[j]);
        ll[j] = f2bf(f[j] - bf2f(hh[j]));
    }
    *(ushort4*)&hi[off + i] = make_ushort4(hh[0], hh[1], hh[2], hh[3]);
    *(ushort4*)&lo[off + i] = make_ushort4(ll[0], ll[1], ll[2], ll[3]);
}

// ---------------- MFMA GEMM: C[n,m] = sum_k A[n,k]*W[m,k] + bias[m] ----------------
// PASSES: 1 = single bf16, 3 = split (AhWh + AhWl + AlWh).
// OMODE: 0 = natural fp32 [N,512], 1 = transposed fp32 [B(,QK),E,T], 2 = natural bf16.
template<int PASSES, int OMODE>
__global__ __launch_bounds__(256) void mfma_gemm(const unsigned short* __restrict__ Ah,
                                                 const unsigned short* __restrict__ Al,
                                                 const unsigned short* __restrict__ Bh,
                                                 const unsigned short* __restrict__ Bl,
                                                 const float* __restrict__ bias,
                                                 const float* __restrict__ bias2,
                                                 void* __restrict__ Cp)
{
    constexpr int NT = (PASSES == 3) ? 4 : 2;
    constexpr int TSZ = 128 * 40;            // padded tile: 128 rows x 40 shorts (80B stride)
    __shared__ short smem[NT * TSZ];
    const int tid = threadIdx.x;
    const int m0 = blockIdx.x * 128;
    const int n0 = blockIdx.y * 128;
    const int wid = tid >> 6, lane = tid & 63;
    const int wn = wid >> 1, wm = wid & 1;
    const int lr = lane & 15, lg = lane >> 4;
    const int kb = lg * 8;

    short* At  = smem;
    short* Alt = smem + ((PASSES == 3) ? TSZ : 0);
    short* Bt  = smem + ((PASSES == 3) ? 2 : 1) * TSZ;
    short* Blt = smem + ((PASSES == 3) ? 3 : 1) * TSZ;

    f32x4 acc[4][4];
#pragma unroll
    for (int i = 0; i < 4; i++)
#pragma unroll
        for (int j = 0; j < 4; j++) acc[i][j] = (f32x4)0.f;

    const int c0 = tid, c1 = tid + 256;
    const int r0 = c0 >> 2, kp0 = (c0 & 3) << 3;
    const int r1 = c1 >> 2, kp1 = (c1 & 3) << 3;

    for (int k0 = 0; k0 < 512; k0 += 32) {
        __syncthreads();
        *(bf16x8*)&At[r0 * 40 + kp0] = *(const bf16x8*)&Ah[(size_t)(n0 + r0) * 512 + k0 + kp0];
        *(bf16x8*)&At[r1 * 40 + kp1] = *(const bf16x8*)&Ah[(size_t)(n0 + r1) * 512 + k0 + kp1];
        *(bf16x8*)&Bt[r0 * 40 + kp0] = *(const bf16x8*)&Bh[(size_t)(m0 + r0) * 512 + k0 + kp0];
        *(bf16x8*)&Bt[r1 * 40 + kp1] = *(const bf16x8*)&Bh[(size_t)(m0 + r1) * 512 + k0 + kp1];
        if (PASSES == 3) {
            *(bf16x8*)&Alt[r0 * 40 + kp0] = *(const bf16x8*)&Al[(size_t)(n0 + r0) * 512 + k0 + kp0];
            *(bf16x8*)&Alt[r1 * 40 + kp1] = *(const bf16x8*)&Al[(size_t)(n0 + r1) * 512 + k0 + kp1];
            *(bf16x8*)&Blt[r0 * 40 + kp0] = *(const bf16x8*)&Bl[(size_t)(m0 + r0) * 512 + k0 + kp0];
            *(bf16x8*)&Blt[r1 * 40 + kp1] = *(const bf16x8*)&Bl[(size_t)(m0 + r1) * 512 + k0 + kp1];
        }
        __syncthreads();
        bf16x8 a[4], b[4];
#pragma unroll
        for (int f = 0; f < 4; f++) {
            a[f] = *(bf16x8*)&At[(wn * 64 + f * 16 + lr) * 40 + kb];
            b[f] = *(bf16x8*)&Bt[(wm * 64 + f * 16 + lr) * 40 + kb];
        }
        if (PASSES == 3) {
            bf16x8 a2[4], b2[4];
#pragma unroll
            for (int f = 0; f < 4; f++) {
                a2[f] = *(bf16x8*)&Alt[(wn * 64 + f * 16 + lr) * 40 + kb];
                b2[f] = *(bf16x8*)&Blt[(wm * 64 + f * 16 + lr) * 40 + kb];
            }
#pragma unroll
            for (int i = 0; i < 4; i++)
#pragma unroll
                for (int j = 0; j < 4; j++) {
                    acc[i][j] = __builtin_amdgcn_mfma_f32_16x16x32_bf16(a[i], b[j], acc[i][j], 0, 0, 0);
                    acc[i][j] = __builtin_amdgcn_mfma_f32_16x16x32_bf16(a[i], b2[j], acc[i][j], 0, 0, 0);
                    acc[i][j] = __builtin_amdgcn_mfma_f32_16x16x32_bf16(a2[i], b[j], acc[i][j], 0, 0, 0);
                }
        } else {
#pragma unroll
            for (int i = 0; i < 4; i++)
#pragma unroll
                for (int j = 0; j < 4; j++)
                    acc[i][j] = __builtin_amdgcn_mfma_f32_16x16x32_bf16(a[i], b[j], acc[i][j], 0, 0, 0);
        }
    }

    const float* bp = (m0 >= 512) ? bias2 : bias;
    const int mb = m0 & 511;
    float bs[4];
#pragma unroll
    for (int j = 0; j < 4; j++) bs[j] = bp[mb + wm * 64 + j * 16 + lr];

    if (OMODE == 1) {
        // transposed write: row = qk*2048 + b*512 + e, col = t (contiguous per fragment)
        float* C = (float*)Cp;
        const int qk = m0 >> 9;
        const int bidx = n0 >> 12;
        const int t0 = (n0 & 4095) + wn * 64;
#pragma unroll
        for (int i = 0; i < 4; i++)
#pragma unroll
            for (int j = 0; j < 4; j++) {
                int t = t0 + i * 16 + lg * 4;
                int e = mb + wm * 64 + j * 16 + lr;
                size_t row = (size_t)(qk * 2048 + bidx * 512 + e);
                float4 o = make_float4(acc[i][j][0] + bs[j], acc[i][j][1] + bs[j],
                                       acc[i][j][2] + bs[j], acc[i][j][3] + bs[j]);
                *(float4*)&C[row * 4096 + t] = o;
            }
    } else if (OMODE == 0) {
        float* C = (float*)Cp;
#pragma unroll
        for (int i = 0; i < 4; i++)
#pragma unroll
            for (int j = 0; j < 4; j++) {
                int m = m0 + wm * 64 + j * 16 + lr;
#pragma unroll
                for (int r = 0; r < 4; r++) {
                    int n = n0 + wn * 64 + i * 16 + lg * 4 + r;
                    C[(size_t)n * 512 + m] = acc[i][j][r] + bs[j];
                }
            }
    } else {
        unsigned short* C = (unsigned short*)Cp;
#pragma unroll
        for (int i = 0; i < 4; i++)
#pragma unroll
            for (int j = 0; j < 4; j++) {
                int m = m0 + wm * 64 + j * 16 + lr;
#pragma unroll
                for (int r = 0; r < 4; r++) {
                    int n = n0 + wn * 64 + i * 16 + lg * 4 + r;
                    C[(size_t)n * 512 + m] = f2bf(acc[i][j][r] + bs[j]);
                }
            }
    }
}

// ================= radix-8 register FFT (N = 4096 = 8^4) =================
// SGN = -1 forward, +1 inverse. LDS swizzle: sw(i) = i + (i>>3) (max 4606).
template<int SGN>
__device__ __forceinline__ void radix8(float* xr, float* xi)
{
    const float C = 0.70710678118654752440f;
    const float S = (float)SGN;
    float t0r = xr[0] + xr[4], t0i = xi[0] + xi[4];
    float t1r = xr[1] + xr[5], t1i = xi[1] + xi[5];
    float t2r = xr[2] + xr[6], t2i = xi[2] + xi[6];
    float t3r = xr[3] + xr[7], t3i = xi[3] + xi[7];
    float u0r = xr[0] - xr[4], u0i = xi[0] - xi[4];
    float a1r = xr[1] - xr[5], a1i = xi[1] - xi[5];
    float a2r = xr[2] - xr[6], a2i = xi[2] - xi[6];
    float a3r = xr[3] - xr[7], a3i = xi[3] - xi[7];
    float u1r = C * (a1r - S * a1i), u1i = C * (S * a1r + a1i);
    float u2r = -S * a2i,            u2i = S * a2r;
    float u3r = -C * (a3r + S * a3i), u3i = C * (S * a3r - a3i);
    // even half (radix-4 DIF)
    float v0r = t0r + t2r, v0i = t0i + t2i;
    float w0r = t0r - t2r, w0i = t0i - t2i;
    float v1r = t1r + t3r, v1i = t1i + t3i;
    float w1r = -S * (t1i - t3i), w1i = S * (t1r - t3r);
    // odd half
    float p0r = u0r + u2r, p0i = u0i + u2i;
    float q0r = u0r - u2r, q0i = u0i - u2i;
    float p1r = u1r + u3r, p1i = u1i + u3i;
    float q1r = -S * (u1i - u3i), q1i = S * (u1r - u3r);
    xr[0] = v0r + v1r; xi[0] = v0i + v1i;
    xr[4] = v0r - v1r; xi[4] = v0i - v1i;
    xr[2] = w0r + w1r; xi[2] = w0i + w1i;
    xr[6] = w0r - w1r; xi[6] = w0i - w1i;
    xr[1] = p0r + p1r; xi[1] = p0i + p1i;
    xr[5] = p0r - p1r; xi[5] = p0i - p1i;
    xr[3] = q0r + q1r; xi[3] = q0i + q1i;
    xr[7] = q0r - q1r; xi[7] = q0i - q1i;
}

__device__ __forceinline__ void twmul(float& xr, float& xi, float wc, float ws)
{
    float a = xr, b = xi;
    xr = a * wc - b * ws;
    xi = a * ws + b * wc;
}

// multiply xr[r],xi[r] by w^r where w = exp(i*ang*n), r = 1..7
__device__ __forceinline__ void twiddle7(float* xr, float* xi, int n, float ang)
{
    float s1, c1;
    __sincosf(ang * (float)n, &s1, &c1);
    float wc = c1, ws = s1;
    twmul(xr[1], xi[1], wc, ws);
#pragma unroll
    for (int r = 2; r < 8; r++) {
        float nc = wc * c1 - ws * s1;
        float ns = wc * s1 + ws * c1;
        wc = nc; ws = ns;
        twmul(xr[r], xi[r], wc, ws);
    }
}

#define SW(i) ((i) + ((i) >> 3))

template<int SGN>
__device__ __forceinline__ void fft_core(float* xr, float* xi,
                                         float* lre, float* lim, int tid)
{
    const float TW = (float)SGN * 6.28318530717958647693f;
    __syncthreads();                         // guard LDS reuse across calls
    // stage 1: M=4096, n=tid, stride 512 (already in regs)
    radix8<SGN>(xr, xi);
    twiddle7(xr, xi, tid, TW / 4096.f);
#pragma unroll
    for (int r = 0; r < 8; r++) {
        int idx = r * 512 + tid;
        lre[SW(idx)] = xr[r]; lim[SW(idx)] = xi[r];
    }
    __syncthreads();
    // stage 2: M=512, sub = tid>>6, n = tid&63, stride 64
    const int b2 = (tid >> 6) * 512, n2 = tid & 63;
#pragma unroll
    for (int s = 0; s < 8; s++) {
        int idx = b2 + n2 + s * 64;
        xr[s] = lre[SW(idx)]; xi[s] = lim[SW(idx)];
    }
    __syncthreads();
    radix8<SGN>(xr, xi);
    twiddle7(xr, xi, n2, TW / 512.f);
#pragma unroll
    for (int r = 0; r < 8; r++) {
        int idx = b2 + r * 64 + n2;
        lre[SW(idx)] = xr[r]; lim[SW(idx)] = xi[r];
    }
    __syncthreads();
    // stage 3: M=64, sub = tid>>3, n = tid&7, stride 8
    const int b3 = (tid >> 3) * 64, n3 = tid & 7;
#pragma unroll
    for (int s = 0; s < 8; s++) {
        int idx = b3 + n3 + s * 8;
        xr[s] = lre[SW(idx)]; xi[s] = lim[SW(idx)];
    }
    __syncthreads();
    radix8<SGN>(xr, xi);
    twiddle7(xr, xi, n3, TW / 64.f);
#pragma unroll
    for (int r = 0; r < 8; r++) {
        int idx = b3 + r * 8 + n3;
        lre[SW(idx)] = xr[r]; lim[SW(idx)] = xi[r];
    }
    __syncthreads();
    // stage 4: M=8, stride 1; scatter to natural frequency order
#pragma unroll
    for (int s = 0; s < 8; s++) {
        int idx = tid * 8 + s;
        xr[s] = lre[SW(idx)]; xi[s] = lim[SW(idx)];
    }
    __syncthreads();
    radix8<SGN>(xr, xi);
    const int fr = ((tid & 7) << 6) | (((tid >> 3) & 7) << 3) | (tid >> 6);
#pragma unroll
    for (int r = 0; r < 8; r++) {
        int f = r * 512 + fr;
        lre[SW(f)] = xr[r]; lim[SW(f)] = xi[r];
    }
    __syncthreads();
}

// ---------------- forward FFT: 4 channels/block, partial product reduce ----------------
__global__ __launch_bounds__(512) void fft_fwd_kernel(const float* __restrict__ Qt,
                                                      const float* __restrict__ Kt,
                                                      float2* __restrict__ prodp)
{
    __shared__ float lre[4608];
    __shared__ float lim[4608];
    const int bid = blockIdx.x;          // 0..511
    const int tid = threadIdx.x;
    const int b = bid >> 7, chunk = bid & 127;
    float par[5] = {0.f, 0.f, 0.f, 0.f, 0.f};
    float pai[4] = {0.f, 0.f, 0.f, 0.f};
    for (int c = 0; c < 4; c++) {
        const int e = chunk * 4 + c;
        const float* q = Qt + ((size_t)(b * 512 + e)) * 4096;
        const float* k = Kt + ((size_t)(b * 512 + e)) * 4096;
        float xr[8], xi[8];
#pragma unroll
        for (int s = 0; s < 8; s++) {
            xr[s] = q[tid + 512 * s];
            xi[s] = k[tid + 512 * s];
        }
        fft_core<-1>(xr, xi, lre, lim, tid);
        // unpack packed real FFTs, accumulate Qf * conj(Kf)
#pragma unroll
        for (int s = 0; s < 4; s++) {
            int f = tid + 512 * s;
            int nf = (4096 - f) & 4095;
            float Ax = lre[SW(f)],  Ay = lim[SW(f)];
            float Bx = lre[SW(nf)], By = lim[SW(nf)];
            float qx = 0.5f * (Ax + Bx), qy = 0.5f * (Ay - By);
            float kx = 0.5f * (Ay + By), ky = -0.5f * (Ax - Bx);
            par[s] += qx * kx + qy * ky;
            pai[s] += qy * kx - qx * ky;
        }
        if (tid == 0) {
            float Ax = lre[SW(2048)], Ay = lim[SW(2048)];
            par[4] += Ax * Ay;       // f = 2048: purely real product
        }
    }
    float2* out = prodp + (size_t)bid * FHP;
#pragma unroll
    for (int s = 0; s < 4; s++)
        out[tid + 512 * s] = make_float2(par[s], pai[s]);
    if (tid == 0) out[2048] = make_float2(par[4], 0.f);
}

// ---------------- reduce partial product spectra ----------------
__global__ __launch_bounds__(256) void reduce_s(const float2* __restrict__ prodp,
                                                float2* __restrict__ S)
{
    const int f = blockIdx.x * 256 + threadIdx.x;
    const int b = blockIdx.y;
    if (f >= FH) return;
    float sx = 0.f, sy = 0.f;
    const float2* p = prodp + (size_t)(b * 128) * FHP + f;
#pragma unroll 8
    for (int j = 0; j < 128; j++) {
        float2 v = p[(size_t)j * FHP];
        sx += v.x; sy += v.y;
    }
    S[b * FHP + f] = make_float2(sx, sy);
}

// ---------------- inverse FFT -> ac_mean ----------------
__global__ __launch_bounds__(512) void ifft_kernel(const float2* __restrict__ S,
                                                   float* __restrict__ acm)
{
    __shared__ float lre[4608];
    __shared__ float lim[4608];
    const int b = blockIdx.x, tid = threadIdx.x;
    float xr[8], xi[8];
#pragma unroll
    for (int s = 0; s < 8; s++) {
        int idx = tid + 512 * s;
        if (idx <= 2048) {
            float2 v = S[b * FHP + idx];
            xr[s] = v.x; xi[s] = v.y;
        } else {
            float2 v = S[b * FHP + (4096 - idx)];
            xr[s] = v.x; xi[s] = -v.y;
        }
    }
    fft_core<1>(xr, xi, lre, lim, tid);
    const float scale = 1.0f / ((float)T_ * (float)E_);
#pragma unroll
    for (int s = 0; s < 8; s++) {
        int p = tid + 512 * s;
        acm[b * T_ + p] = lre[SW(p)] * scale;
    }
}

// ---------------- top-k (24) + softmax, per batch ----------------
__global__ __launch_bounds__(256) void topk_kernel(const float* __restrict__ acm,
                                                   int* __restrict__ delays,
                                                   float* __restrict__ weights)
{
    __shared__ float vals[4096];
    __shared__ float bv[256];
    __shared__ int   bi[256];
    __shared__ float topv[TOPK];
    const int b = blockIdx.x, tid = threadIdx.x;
#pragma unroll
    for (int s = 0; s < 16; s++) vals[tid + 256 * s] = acm[b * T_ + tid + 256 * s];
    __syncthreads();
    for (int it = 0; it < TOPK; it++) {
        float best = -INFINITY; int bidx = 0;
#pragma unroll
        for (int s = 0; s < 16; s++) {
            int idx = tid * 16 + s;
            float v = vals[idx];
            if (v > best) { best = v; bidx = idx; }
        }
        bv[tid] = best; bi[tid] = bidx;
        __syncthreads();
        for (int off = 128; off > 0; off >>= 1) {
            if (tid < off) {
                if (bv[tid + off] > bv[tid] ||
                    (bv[tid + off] == bv[tid] && bi[tid + off] < bi[tid])) {
                    bv[tid] = bv[tid + off]; bi[tid] = bi[tid + off];
                }
            }
            __syncthreads();
        }
        if (tid == 0) {
            delays[b * TOPK + it] = bi[0];
            topv[it] = bv[0];
            vals[bi[0]] = -INFINITY;
        }
        __syncthreads();
    }
    if (tid == 0) {
        float mx = topv[0];
        float w[TOPK], sum = 0.f;
        for (int i = 0; i < TOPK; i++) { w[i] = expf(topv[i] - mx); sum += w[i]; }
        for (int i = 0; i < TOPK; i++) weights[b * TOPK + i] = w[i] / sum;
    }
}

// ---------------- agg: weighted circular gather of bf16 V ----------------
__global__ __launch_bounds__(256) void agg_kernel(const unsigned short* __restrict__ V,
                                                  const int* __restrict__ delays,
                                                  const float* __restrict__ wts,
                                                  unsigned short* __restrict__ agg)
{
    __shared__ int   dly[B_][TOPK];
    __shared__ float wt[B_][TOPK];
    const int tid = threadIdx.x, b = blockIdx.y;
    if (tid < B_ * TOPK) {
        dly[tid / TOPK][tid % TOPK] = delays[tid];
        wt[tid / TOPK][tid % TOPK]  = wts[tid];
    }
    __syncthreads();
    const int lane = tid & 63, w = tid >> 6;
    const int t = blockIdx.x * 4 + w;
    const int e8 = lane * 8;
    const int h = e8 >> 6;
    const int c = (b * H_ + h) % B_;
    const unsigned short* Vb = V + (size_t)b * T_ * E_;
    float acc[8];
#pragma unroll
    for (int j = 0; j < 8; j++) acc[j] = 0.f;
#pragma unroll
    for (int i = 0; i < TOPK; i++) {
        int tt = (t + dly[c][i]) & (T_ - 1);
        bf16x8 v = *(const bf16x8*)&Vb[(size_t)tt * E_ + e8];
        float wg = wt[c][i];
#pragma unroll
        for (int j = 0; j < 8; j++)
            acc[j] += wg * bf2f((unsigned short)v[j]);
    }
    bf16x8 o;
#pragma unroll
    for (int j = 0; j < 8; j++) o[j] = (short)f2bf(acc[j]);
    *(bf16x8*)&agg[((size_t)b * T_ + t) * E_ + e8] = o;
}

// ---------------- launch ----------------
extern "C" void kernel_launch(void* const* d_in, const int* in_sizes, int n_in,
                              void* d_out, int out_size, void* d_ws, size_t ws_size,
                              hipStream_t stream)
{
    const float* hidden = (const float*)d_in[0];
    const float* Wq = (const float*)d_in[1]; const float* bq = (const float*)d_in[2];
    const float* Wk = (const float*)d_in[3]; const float* bk = (const float*)d_in[4];
    const float* Wv = (const float*)d_in[5]; const float* bv = (const float*)d_in[6];
    const float* Wo = (const float*)d_in[7]; const float* bo = (const float*)d_in[8];

    char* ws = (char*)d_ws;
    const size_t QT_OFF  = 0;                  // 33.5 MB fp32 [B,E,T] (Q)
    const size_t KT_OFF  = 33554432;           // 33.5 MB (K) — contiguous after Q
    const size_t VB_OFF  = 67108864;           // 16.8 MB bf16 [B,T,E]
    const size_t BIG_OFF = 83886080;           // 16.8 MB: Ah, later prodp (8.5 MB)
    const size_t BIG2_OFF= 100663296;          // 16.8 MB: Al, later agg bf16
    const size_t WHI_OFF = 117702656;          // 2 MB  (4x 512x512 bf16: Wq,Wk,Wv,Wo)
    const size_t WLO_OFF = 119799808;          // 2 MB
    const size_t S_OFF   = 121896960;          // 66 KB
    const size_t ACM_OFF = 121963008;          // 64 KB
    const size_t DEL_OFF = 122028544;          // 384 B
    const size_t WTS_OFF = 122028928;          // 384 B
    if (ws_size < 122029312) return;

    float*  Qt   = (float*)(ws + QT_OFF);      // K half lives at rows 2048..4095
    unsigned short* Vb  = (unsigned short*)(ws + VB_OFF);
    unsigned short* Ah  = (unsigned short*)(ws + BIG_OFF);
    unsigned short* Al  = (unsigned short*)(ws + BIG2_OFF);
    float2* prodp = (float2*)(ws + BIG_OFF);   // aliases Ah (dead after V GEMM)
    unsigned short* Ag  = (unsigned short*)(ws + BIG2_OFF); // aliases Al (dead after QK GEMM)
    unsigned short* Whi = (unsigned short*)(ws + WHI_OFF);
    unsigned short* Wlo = (unsigned short*)(ws + WLO_OFF);
    float2* S    = (float2*)(ws + S_OFF);
    float*  acm  = (float*)(ws + ACM_OFF);
    int*    delays = (int*)(ws + DEL_OFF);
    float*  wts    = (float*)(ws + WTS_OFF);

    unsigned short* Wvh = Whi + 2 * 262144;
    unsigned short* Woh = Whi + 3 * 262144;

    // splits
    split_hidden<<<8192, 256, 0, stream>>>(hidden, Ah, Al);
    dim3 wg(256, 4);
    split_w4<<<wg, 256, 0, stream>>>(Wq, Wk, Wv, Wo, Whi, Wlo);

    // fused Q+K GEMM (M = 1024 over [Wq;Wk]), transposed output -> Qt/Kt
    dim3 gqk(8, 128);
    mfma_gemm<3, 1><<<gqk, 256, 0, stream>>>(Ah, Al, Whi, Wlo, bq, bk, Qt);
    // V GEMM (bf16 out)
    dim3 gv(4, 128);
    mfma_gemm<1, 2><<<gv, 256, 0, stream>>>(Ah, Ah, Wvh, Wvh, bv, bv, Vb);

    // autocorrelation spectrum: 512 blocks x 4 channels, partial-reduced
    fft_fwd_kernel<<<512, 512, 0, stream>>>(Qt, (float*)(ws + KT_OFF), prodp);
    dim3 rg((FH + 255) / 256, B_);
    reduce_s<<<rg, 256, 0, stream>>>(prodp, S);
    ifft_kernel<<<B_, 512, 0, stream>>>(S, acm);
    topk_kernel<<<B_, 256, 0, stream>>>(acm, delays, wts);

    // weighted circular gather (bf16 in/out) + output projection
    dim3 ag(T_ / 4, B_);
    agg_kernel<<<ag, 256, 0, stream>>>(Vb, delays, wts, Ag);
    mfma_gemm<1, 0><<<gv, 256, 0, stream>>>(Ag, Ag, Woh, Woh, bo, bo, (float*)d_out);
}